// Round 11
// baseline (4647.901 us; speedup 1.0000x reference)
//
#include <hip/hip_runtime.h>

// ---------------------------------------------------------------------------
// CellVGAE GCN encoder: x -> GCN(512,128)+ReLU -> GCN(128,128)+ReLU
//                         -> {GCN(128,64) mean, GCN(128,64) log_std}
// Round 16 (= r15 resubmit; compile error was a trailing-backslash comment
//   that line-spliced away the tcA declaration):
//   Flag-gated producer/consumer fusion of {prop1 || gemm2} and
//   {prop2 || gemm3} in single dispatches:
//   - gemm tile t reads A rows 64t..64t+63 only (row-local) -> per-tile
//     counter released by prop waves (threadfence + device-scope atomics,
//     protocol = r13's gbar which passed bit-exact).
//   - Triple-buffer WAR fix for free: d_out (25.6MB) is gemm2's scratch
//     output, overwritten by prop_fin's final write.
//   - Progress order-independent: 782 gemm blocks can all spin resident
//     while prop blocks fit alongside (no deadlock).
//   10 -> 8 nodes. Arithmetic identical to r14 -> absmax unchanged.
// ---------------------------------------------------------------------------

using u16 = unsigned short;
typedef __attribute__((ext_vector_type(8))) short short8;
typedef __attribute__((ext_vector_type(4))) float f32x4;

__device__ __forceinline__ void split_bf16(float f, u16& hi, u16& lo) {
    unsigned b = __float_as_uint(f);
    hi = (u16)(b >> 16);
    float rem = f - __uint_as_float(b & 0xFFFF0000u);
    lo = (u16)(__float_as_uint(rem) >> 16);
}

#define TILE_OFF(t) ((t) * 520)

// Block-wide mode detect: 1 = int64 edge_index, 0 = int32.
__device__ __forceinline__ int block_mode(const int* __restrict__ ew, int* sflag) {
    if (threadIdx.x == 0) *sflag = 0;
    __syncthreads();
    if (ew[2 * (int)threadIdx.x + 1] != 0) atomicOr(sflag, 1);
    __syncthreads();
    return *sflag ? 0 : 1;
}

// ---- GEMM tile: C[64 x 128] block = dis (.) (A @ B) -----------------------
// r12-verbatim body (bit-validated r12/r13/r14). A via LDS (lane-seq map,
// conflicts=0); B frags direct from global in MFMA fragment order.
__device__ __forceinline__ void gemm_tile(
    const float* __restrict__ A, const u16* __restrict__ Bfh,
    const u16* __restrict__ Bfl, const float* __restrict__ dis,
    float* __restrict__ C, int N, int K, int tile,
    u16* AsH, u16* AsL) {
    const int tid = threadIdx.x;
    const int w = tid >> 6, lane = tid & 63;
    const int m16 = lane & 15, quad = lane >> 4;
    const int row0 = tile * 64;

    const int s_ar = w * 16 + (lane & 15);
    const int s_ak = (lane >> 4) * 8;
    const int a_dst = TILE_OFF(w) + lane * 8;

    const int R = (w >> 1) * 32, Cc = (w & 1) * 64;
    const int atile = (w >> 1) * 2;
    const int btile = (w & 1) * 4;

    const int ksteps = K >> 5;
    const u16* bfh = Bfh + ((size_t)btile * ksteps) * 512 + lane * 8;
    const u16* bfl = Bfl + ((size_t)btile * ksteps) * 512 + lane * 8;

    f32x4 acc[2][4];
#pragma unroll
    for (int i = 0; i < 2; ++i)
#pragma unroll
        for (int j = 0; j < 4; ++j) acc[i][j] = (f32x4)0.f;

    float dr[2][4];
#pragma unroll
    for (int i = 0; i < 2; ++i)
#pragma unroll
        for (int r = 0; r < 4; ++r) {
            int gr = row0 + R + i * 16 + quad * 4 + r;
            dr[i][r] = dis[gr < N ? gr : N - 1];
        }

    const int grow = row0 + s_ar;
    const bool ok = (grow < N);
    const float* aptr = A + (size_t)grow * K + s_ak;

    float av[8];
    {
        f32x4 v0 = (f32x4)0.f, v1 = (f32x4)0.f;
        if (ok) { v0 = *(const f32x4*)&aptr[0]; v1 = *(const f32x4*)&aptr[4]; }
#pragma unroll
        for (int q = 0; q < 4; ++q) { av[q] = v0[q]; av[4 + q] = v1[q]; }
    }

    for (int ks = 0; ks < ksteps; ++ks) {
        short8 fbh[4], fbl[4];
#pragma unroll
        for (int j = 0; j < 4; ++j) {
            fbh[j] = *(const short8*)(bfh + (size_t)(j * ksteps + ks) * 512);
            fbl[j] = *(const short8*)(bfl + (size_t)(j * ksteps + ks) * 512);
        }

        short8 ah, al;
#pragma unroll
        for (int q = 0; q < 8; ++q) {
            u16 h, l;
            split_bf16(av[q], h, l);
            ah[q] = (short)h;
            al[q] = (short)l;
        }
        __syncthreads();
        *(short8*)&AsH[a_dst] = ah;
        *(short8*)&AsL[a_dst] = al;
        __syncthreads();

        if (ks + 1 < ksteps) {
            const int k0 = (ks + 1) * 32;
            f32x4 v0 = (f32x4)0.f, v1 = (f32x4)0.f;
            if (ok) { v0 = *(const f32x4*)&aptr[k0]; v1 = *(const f32x4*)&aptr[k0 + 4]; }
#pragma unroll
            for (int q = 0; q < 4; ++q) { av[q] = v0[q]; av[4 + q] = v1[q]; }
        }

        short8 fah[2], fal[2];
#pragma unroll
        for (int i = 0; i < 2; ++i) {
            fah[i] = *(const short8*)&AsH[TILE_OFF(atile + i) + lane * 8];
            fal[i] = *(const short8*)&AsL[TILE_OFF(atile + i) + lane * 8];
        }

#pragma unroll
        for (int i = 0; i < 2; ++i)
#pragma unroll
            for (int j = 0; j < 4; ++j) {
                acc[i][j] = __builtin_amdgcn_mfma_f32_16x16x32_bf16(
                    fah[i], fbh[j], acc[i][j], 0, 0, 0);
                acc[i][j] = __builtin_amdgcn_mfma_f32_16x16x32_bf16(
                    fah[i], fbl[j], acc[i][j], 0, 0, 0);
                acc[i][j] = __builtin_amdgcn_mfma_f32_16x16x32_bf16(
                    fal[i], fbh[j], acc[i][j], 0, 0, 0);
            }
    }

#pragma unroll
    for (int i = 0; i < 2; ++i) {
#pragma unroll
        for (int r = 0; r < 4; ++r) {
            int gr = row0 + R + i * 16 + quad * 4 + r;
            if (gr < N) {
#pragma unroll
                for (int j = 0; j < 4; ++j)
                    C[(size_t)gr * 128 + Cc + j * 16 + m16] = acc[i][j][r] * dr[i][r];
            }
        }
    }
}

// ---- K1: weight conversion (frag order) + degree count --------------------
__global__ void conv_deg_kernel(
    const float* __restrict__ W1, const float* __restrict__ W2,
    const float* __restrict__ Wm, const float* __restrict__ Ws,
    u16* __restrict__ B1h, u16* __restrict__ B1l,
    u16* __restrict__ B2h, u16* __restrict__ B2l,
    u16* __restrict__ Bch, u16* __restrict__ Bcl,
    const int* __restrict__ ew, int* __restrict__ deg, int E) {
    __shared__ int sflag;
    int mode = block_mode(ew, &sflag);
    int gtid = blockIdx.x * 256 + threadIdx.x;
    if (gtid < 98304) {
        int idx = gtid;
        u16 h, l;
        if (idx < 65536) {                 // W1: 512x128, ksteps=16
            int t = idx >> 13, ks = (idx >> 9) & 15, L = (idx >> 3) & 63, q = idx & 7;
            int col = t * 16 + (L & 15);
            int k = ks * 32 + (L >> 4) * 8 + q;
            split_bf16(W1[k * 128 + col], h, l);
            B1h[idx] = h; B1l[idx] = l;
        } else if (idx < 81920) {          // W2: 128x128, ksteps=4
            int o = idx - 65536;
            int t = o >> 11, ks = (o >> 9) & 3, L = (o >> 3) & 63, q = o & 7;
            int col = t * 16 + (L & 15);
            int k = ks * 32 + (L >> 4) * 8 + q;
            split_bf16(W2[k * 128 + col], h, l);
            B2h[o] = h; B2l[o] = l;
        } else {                           // [Wm|Ws]: 128x128, ksteps=4
            int o = idx - 81920;
            int t = o >> 11, ks = (o >> 9) & 3, L = (o >> 3) & 63, q = o & 7;
            int col = t * 16 + (L & 15);
            int k = ks * 32 + (L >> 4) * 8 + q;
            float f = (col < 64) ? Wm[k * 64 + col] : Ws[k * 64 + (col - 64)];
            split_bf16(f, h, l);
            Bch[o] = h; Bcl[o] = l;
        }
    }
    if (gtid < E) {
        int d = mode ? ew[2 * E + 2 * gtid] : ew[E + gtid];
        atomicAdd(&deg[d], 1);
    }
}

// ---- K2: per-chunk exclusive scan + dis = rsqrt(deg+1) --------------------
__global__ void scan_block_kernel(const int* __restrict__ deg, int* __restrict__ rowptr,
                                  int* __restrict__ aux, float* __restrict__ dis, int N) {
    __shared__ int s[256];
    int i = blockIdx.x * 256 + threadIdx.x;
    int v = (i < N) ? deg[i] : 0;
    if (i < N) dis[i] = rsqrtf((float)v + 1.0f);
    s[threadIdx.x] = v;
    __syncthreads();
    for (int off = 1; off < 256; off <<= 1) {
        int t = (threadIdx.x >= off) ? s[threadIdx.x - off] : 0;
        __syncthreads();
        s[threadIdx.x] += t;
        __syncthreads();
    }
    if (i < N) rowptr[i] = s[threadIdx.x] - v;
    if (threadIdx.x == 255) aux[blockIdx.x] = s[255];
}

// ---- K3: offsets with inline aux scan + cursor init -----------------------
__global__ void offsets_kernel(int* __restrict__ rowptr, const int* __restrict__ aux,
                               int* __restrict__ cursor, int N, int E, int nch) {
    __shared__ int s[256];
    const int b = blockIdx.x, tid = threadIdx.x;
    int v = (tid < nch) ? aux[tid] : 0;
    s[tid] = v;
    __syncthreads();
    for (int off = 1; off < 256; off <<= 1) {
        int t = (tid >= off) ? s[tid - off] : 0;
        __syncthreads();
        s[tid] += t;
        __syncthreads();
    }
    const int excl = (b == 0) ? 0 : s[b - 1];
    int i = b * 256 + tid;
    if (i < N) {
        int rp = rowptr[i] + excl;
        rowptr[i] = rp;
        cursor[i] = rp;
    }
    if (b == 0 && tid == 0) rowptr[N] = E;
}

// ---- K4: gemm1 (blocks < gtiles) PARALLEL fill_csr (remaining blocks) -----
__global__ __launch_bounds__(256) void gemm1_fill_kernel(
    const float* __restrict__ A, const u16* __restrict__ Bfh,
    const u16* __restrict__ Bfl, const float* __restrict__ dis,
    float* __restrict__ C, int N, int gtiles,
    const int* __restrict__ ew, int* __restrict__ cursor,
    int* __restrict__ csr_src, int E) {
    __shared__ __align__(16) u16 AsH[4 * 520], AsL[4 * 520];
    __shared__ int sflag;
    if ((int)blockIdx.x < gtiles) {
        gemm_tile(A, Bfh, Bfl, dis, C, N, 512, blockIdx.x, AsH, AsL);
    } else {
        int mode = block_mode(ew, &sflag);
        int e = ((int)blockIdx.x - gtiles) * 256 + (int)threadIdx.x;
        if (e < E) {
            int s = mode ? ew[2 * e] : ew[e];
            int d = mode ? ew[2 * E + 2 * e] : ew[E + e];
            int pos = atomicAdd(&cursor[d], 1);
            csr_src[pos] = s;
        }
    }
}

// ---- propagate body (r14-verbatim math) + per-tile release flag -----------
__device__ __forceinline__ void prop_node(
    const float* __restrict__ hs, const int* __restrict__ rowptr,
    const int* __restrict__ csr_src, const float* __restrict__ dis,
    const float* __restrict__ bias, float* __restrict__ out,
    int v, int lane, int* __restrict__ tilecnt) {
    const int half = lane >> 5, c = lane & 31;
    const int f4 = c * 4;
    const float dv = dis[v];
    f32x4 acc = (f32x4)0.f;
    const int beg = rowptr[v], end = rowptr[v + 1];
    int i = beg;
    for (; i + 8 <= end; i += 8) {
        int s[4];
        f32x4 g[4];
#pragma unroll
        for (int u = 0; u < 4; ++u) s[u] = csr_src[i + 2 * u + half];
#pragma unroll
        for (int u = 0; u < 4; ++u) g[u] = *(const f32x4*)&hs[(size_t)s[u] * 128 + f4];
#pragma unroll
        for (int u = 0; u < 4; ++u) acc += g[u];
    }
    for (; i + 2 <= end; i += 2) {
        int s = csr_src[i + half];
        acc += *(const f32x4*)&hs[(size_t)s * 128 + f4];
    }
    if (i < end && half == 0) {
        int s = csr_src[i];
        acc += *(const f32x4*)&hs[(size_t)s * 128 + f4];
    }
#pragma unroll
    for (int k = 0; k < 4; ++k) acc[k] += __shfl_xor(acc[k], 32);
    if (half == 0) {
        const f32x4 hv = *(const f32x4*)&hs[(size_t)v * 128 + f4];
        const f32x4 b = *(const f32x4*)&bias[f4];
        f32x4 o;
#pragma unroll
        for (int k = 0; k < 4; ++k) {
            float t = dv * (acc[k] + hv[k]) + b[k];
            o[k] = fmaxf(t, 0.f);                 // both hidden layers: relu
        }
        *(f32x4*)&out[(size_t)v * 128 + f4] = o;
    }
    __threadfence();                              // wave stores visible
    if (lane == 0)
        __hip_atomic_fetch_add(&tilecnt[v >> 6], 1,
                               __ATOMIC_RELEASE, __HIP_MEMORY_SCOPE_AGENT);
}

// ---- K5/K6: {propagate || next-layer gemm} flag-gated pipeline ------------
// Blocks [0,pb): prop role (1 wave/node, writes prop_out rows, bumps tile
// counter). Blocks [pb,pb+gtiles): gemm role — spin until A-tile rows ready
// (target = min(64, N-64t)), then r12-verbatim gemm tile A=prop_out -> gemm_out.
__global__ __launch_bounds__(256) void prop_gemm_kernel(
    const float* __restrict__ hs_in, const int* __restrict__ rowptr,
    const int* __restrict__ csr_src, const float* __restrict__ dis,
    const float* __restrict__ bias, float* __restrict__ prop_out,
    const u16* __restrict__ Bfh, const u16* __restrict__ Bfl,
    float* __restrict__ gemm_out, int* __restrict__ tilecnt,
    int N, int pb) {
    __shared__ __align__(16) u16 AsH[4 * 520], AsL[4 * 520];
    const int bid = blockIdx.x;
    if (bid < pb) {
        int wave = (bid * 256 + (int)threadIdx.x) >> 6;
        int lane = threadIdx.x & 63;
        if (wave >= N) return;
        prop_node(hs_in, rowptr, csr_src, dis, bias, prop_out, wave, lane, tilecnt);
    } else {
        const int t = bid - pb;
        if (threadIdx.x == 0) {
            const int base = t * 64;
            const int target = (N - base < 64) ? (N - base) : 64;
            while (__hip_atomic_load(&tilecnt[t], __ATOMIC_ACQUIRE,
                                     __HIP_MEMORY_SCOPE_AGENT) < target)
                __builtin_amdgcn_s_sleep(8);
            __threadfence();
        }
        __syncthreads();
        gemm_tile(prop_out, Bfh, Bfl, dis, gemm_out, N, 128, t, AsH, AsL);
    }
}

// ---- final propagate: split into z_mean / z_log_std -----------------------
__global__ void __launch_bounds__(256) propagate_final_kernel(
    const float* __restrict__ hs, const int* __restrict__ rowptr,
    const int* __restrict__ csr_src, const float* __restrict__ dis,
    const float* __restrict__ bm, const float* __restrict__ bs,
    float* __restrict__ out, int N) {
    int wave = (blockIdx.x * 256 + threadIdx.x) >> 6;
    int lane = threadIdx.x & 63;
    if (wave >= N) return;
    const int v = wave;
    const int half = lane >> 5, c = lane & 31;
    const int f4 = c * 4;
    const float dv = dis[v];
    f32x4 acc = (f32x4)0.f;
    const int beg = rowptr[v], end = rowptr[v + 1];
    int i = beg;
    for (; i + 8 <= end; i += 8) {
        int s[4];
        f32x4 g[4];
#pragma unroll
        for (int u = 0; u < 4; ++u) s[u] = csr_src[i + 2 * u + half];
#pragma unroll
        for (int u = 0; u < 4; ++u) g[u] = *(const f32x4*)&hs[(size_t)s[u] * 128 + f4];
#pragma unroll
        for (int u = 0; u < 4; ++u) acc += g[u];
    }
    for (; i + 2 <= end; i += 2) {
        int s = csr_src[i + half];
        acc += *(const f32x4*)&hs[(size_t)s * 128 + f4];
    }
    if (i < end && half == 0) {
        int s = csr_src[i];
        acc += *(const f32x4*)&hs[(size_t)s * 128 + f4];
    }
#pragma unroll
    for (int k = 0; k < 4; ++k) acc[k] += __shfl_xor(acc[k], 32);
    if (half == 0) {
        const f32x4 hv = *(const f32x4*)&hs[(size_t)v * 128 + f4];
        f32x4 o;
        if (f4 < 64) {                          // z_mean
            const f32x4 b = *(const f32x4*)&bm[f4];
#pragma unroll
            for (int k = 0; k < 4; ++k) o[k] = dv * (acc[k] + hv[k]) + b[k];
            *(f32x4*)&out[(size_t)v * 64 + f4] = o;
        } else {                                // z_log_std
            const int g = f4 - 64;
            const f32x4 b = *(const f32x4*)&bs[g];
#pragma unroll
            for (int k = 0; k < 4; ++k) o[k] = dv * (acc[k] + hv[k]) + b[k];
            *(f32x4*)&out[(size_t)N * 64 + (size_t)v * 64 + g] = o;
        }
    }
}

extern "C" void kernel_launch(void* const* d_in, const int* in_sizes, int n_in,
                              void* d_out, int out_size, void* d_ws, size_t ws_size,
                              hipStream_t stream) {
    const float* x  = (const float*)d_in[0];
    const int*   ew = (const int*)d_in[1];
    const float* W1 = (const float*)d_in[2];
    const float* b1 = (const float*)d_in[3];
    const float* W2 = (const float*)d_in[4];
    const float* b2 = (const float*)d_in[5];
    const float* Wm = (const float*)d_in[6];
    const float* bm = (const float*)d_in[7];
    const float* Ws = (const float*)d_in[8];
    const float* bs = (const float*)d_in[9];
    float* out = (float*)d_out;

    const int IN = 512, H = 128;
    const int N = in_sizes[0] / IN;     // 50000
    const int E = in_sizes[1] / 2;      // 800000

    const int gtiles = (N + 63) / 64;

    // ---- workspace (~55.6 MB < proven-safe 58.47 MB) -----------------------
    char* base = (char*)d_ws;
    size_t off = 0;
    auto alloc = [&](size_t bytes) -> char* {
        char* p = base + off;
        off = (off + bytes + 255) & ~(size_t)255;
        return p;
    };
    // deg + tcA + tcB are contiguous and zeroed by ONE memset below.
    int*   deg     = (int*)  alloc((size_t)N * 4);
    int*   tcA     = (int*)  alloc((size_t)gtiles * 4);
    int*   tcB     = (int*)  alloc((size_t)gtiles * 4);
    int*   cursor  = (int*)  alloc((size_t)N * 4);      // init in offsets
    float* dis     = (float*)alloc((size_t)N * 4);
    int*   rowptr  = (int*)  alloc((size_t)(N + 1) * 4);
    int*   aux     = (int*)  alloc(256 * 4);
    int*   csr_src = (int*)  alloc((size_t)E * 4);
    u16*   B1h     = (u16*)  alloc((size_t)IN * H * 2);
    u16*   B1l     = (u16*)  alloc((size_t)IN * H * 2);
    u16*   B2h     = (u16*)  alloc((size_t)H * H * 2);
    u16*   B2l     = (u16*)  alloc((size_t)H * H * 2);
    u16*   Bch     = (u16*)  alloc((size_t)H * H * 2);
    u16*   Bcl     = (u16*)  alloc((size_t)H * H * 2);
    float* hA      = (float*)alloc((size_t)N * H * 4);
    float* hB      = (float*)alloc((size_t)N * H * 4);
    float* outC    = out;               // d_out doubles as gemm2 scratch;
                                        // prop_fin overwrites it last.
    (void)ws_size; (void)n_in; (void)out_size;

    // zero deg + both tile counters in one contiguous memset
    (void)hipMemsetAsync(deg, 0, (size_t)((char*)cursor - (char*)deg), stream);

    const int eblocks = (E + 255) / 256;
    const int nblocks = (N + 255) / 256;
    const int nch = nblocks;
    const int pblocks = (N * 64 + 255) / 256;

    // K1: conv + deg
    conv_deg_kernel<<<eblocks, 256, 0, stream>>>(
        W1, W2, Wm, Ws, B1h, B1l, B2h, B2l, Bch, Bcl, ew, deg, E);
    // K2: chunk scan + dis
    scan_block_kernel<<<nblocks, 256, 0, stream>>>(deg, rowptr, aux, dis, N);
    // K3: offsets (inline aux scan) + cursor init
    offsets_kernel<<<nblocks, 256, 0, stream>>>(rowptr, aux, cursor, N, E, nch);
    // K4: gemm1 || fill_csr
    gemm1_fill_kernel<<<gtiles + eblocks, 256, 0, stream>>>(
        x, B1h, B1l, dis, hA, N, gtiles, ew, cursor, csr_src, E);
    // K5: prop1 (hA->hB) || gemm2 (hB->outC), flag-gated
    prop_gemm_kernel<<<pblocks + gtiles, 256, 0, stream>>>(
        hA, rowptr, csr_src, dis, b1, hB, B2h, B2l, outC, tcA, N, pblocks);
    // K6: prop2 (outC->hA) || gemm3 (hA->hB), flag-gated
    prop_gemm_kernel<<<pblocks + gtiles, 256, 0, stream>>>(
        outC, rowptr, csr_src, dis, b2, hA, Bch, Bcl, hB, tcB, N, pblocks);
    // K7: final prop (hB -> out, overwrites scratch)
    propagate_final_kernel<<<pblocks, 256, 0, stream>>>(hB, rowptr, csr_src, dis,
                                                        bm, bs, out, N);
}

// Round 12
// 500.997 us; speedup vs baseline: 9.2773x; 9.2773x over previous
//
#include <hip/hip_runtime.h>

// ---------------------------------------------------------------------------
// CellVGAE GCN encoder: x -> GCN(512,128)+ReLU -> GCN(128,128)+ReLU
//                         -> {GCN(128,64) mean, GCN(128,64) log_std}
// Round 17 (base r14 = 451.8us; r16 flag-pipeline = 10x regression because
//   device-scope acquire/release thrashes the non-coherent per-XCD L2s —
//   inter-block sync is off the table on gfx950):
//   - Split-K(2) for gemm1: K=512 -> two 8-step halves per 64-row tile,
//     1564 gemm blocks (2x concurrency, half the barrier-locked chain).
//     Partials combined with RELAXED native f32 atomics (unsafeAtomicAdd,
//     no fence -> no L2 invalidation; dispatch boundary provides ordering).
//     Exactly 2 adds onto exact zero => deterministic result; delta vs
//     serial sum ~2^-24, far below the dominating bf16-split error.
//   - hA zero-init folded into K3 (offsets) as grid-stride f32x4 stores.
//   - gemm2/3 (4-step chains) unchanged; props r14-verbatim.
// ---------------------------------------------------------------------------

using u16 = unsigned short;
typedef __attribute__((ext_vector_type(8))) short short8;
typedef __attribute__((ext_vector_type(4))) float f32x4;

__device__ __forceinline__ void split_bf16(float f, u16& hi, u16& lo) {
    unsigned b = __float_as_uint(f);
    hi = (u16)(b >> 16);
    float rem = f - __uint_as_float(b & 0xFFFF0000u);
    lo = (u16)(__float_as_uint(rem) >> 16);
}

#define TILE_OFF(t) ((t) * 520)

// Block-wide mode detect: 1 = int64 edge_index, 0 = int32.
__device__ __forceinline__ int block_mode(const int* __restrict__ ew, int* sflag) {
    if (threadIdx.x == 0) *sflag = 0;
    __syncthreads();
    if (ew[2 * (int)threadIdx.x + 1] != 0) atomicOr(sflag, 1);
    __syncthreads();
    return *sflag ? 0 : 1;
}

// ---- GEMM tile: C[64 x 128] block += / = dis (.) (A[:,kb*32:ke*32] @ B) ---
// r12-verbatim body (bit-validated r12/r13/r14) generalized with a K-step
// range [kb,ke) and an atomic-combine epilogue. A via LDS (lane-seq map,
// conflicts=0); B frags direct from global in MFMA fragment order.
__device__ __forceinline__ void gemm_tile(
    const float* __restrict__ A, const u16* __restrict__ Bfh,
    const u16* __restrict__ Bfl, const float* __restrict__ dis,
    float* __restrict__ C, int N, int K, int tile, int kb, int ke,
    int atomic, u16* AsH, u16* AsL) {
    const int tid = threadIdx.x;
    const int w = tid >> 6, lane = tid & 63;
    const int m16 = lane & 15, quad = lane >> 4;
    const int row0 = tile * 64;

    const int s_ar = w * 16 + (lane & 15);
    const int s_ak = (lane >> 4) * 8;
    const int a_dst = TILE_OFF(w) + lane * 8;

    const int R = (w >> 1) * 32, Cc = (w & 1) * 64;
    const int atile = (w >> 1) * 2;
    const int btile = (w & 1) * 4;

    const int ksteps = K >> 5;                 // layout stride (frag order)
    const u16* bfh = Bfh + ((size_t)btile * ksteps) * 512 + lane * 8;
    const u16* bfl = Bfl + ((size_t)btile * ksteps) * 512 + lane * 8;

    f32x4 acc[2][4];
#pragma unroll
    for (int i = 0; i < 2; ++i)
#pragma unroll
        for (int j = 0; j < 4; ++j) acc[i][j] = (f32x4)0.f;

    float dr[2][4];
#pragma unroll
    for (int i = 0; i < 2; ++i)
#pragma unroll
        for (int r = 0; r < 4; ++r) {
            int gr = row0 + R + i * 16 + quad * 4 + r;
            dr[i][r] = dis[gr < N ? gr : N - 1];
        }

    const int grow = row0 + s_ar;
    const bool ok = (grow < N);
    const float* aptr = A + (size_t)grow * K + s_ak;

    float av[8];
    {
        const int k0 = kb * 32;
        f32x4 v0 = (f32x4)0.f, v1 = (f32x4)0.f;
        if (ok) { v0 = *(const f32x4*)&aptr[k0]; v1 = *(const f32x4*)&aptr[k0 + 4]; }
#pragma unroll
        for (int q = 0; q < 4; ++q) { av[q] = v0[q]; av[4 + q] = v1[q]; }
    }

    for (int ks = kb; ks < ke; ++ks) {
        short8 fbh[4], fbl[4];
#pragma unroll
        for (int j = 0; j < 4; ++j) {
            fbh[j] = *(const short8*)(bfh + (size_t)(j * ksteps + ks) * 512);
            fbl[j] = *(const short8*)(bfl + (size_t)(j * ksteps + ks) * 512);
        }

        short8 ah, al;
#pragma unroll
        for (int q = 0; q < 8; ++q) {
            u16 h, l;
            split_bf16(av[q], h, l);
            ah[q] = (short)h;
            al[q] = (short)l;
        }
        __syncthreads();
        *(short8*)&AsH[a_dst] = ah;
        *(short8*)&AsL[a_dst] = al;
        __syncthreads();

        if (ks + 1 < ke) {
            const int k0 = (ks + 1) * 32;
            f32x4 v0 = (f32x4)0.f, v1 = (f32x4)0.f;
            if (ok) { v0 = *(const f32x4*)&aptr[k0]; v1 = *(const f32x4*)&aptr[k0 + 4]; }
#pragma unroll
            for (int q = 0; q < 4; ++q) { av[q] = v0[q]; av[4 + q] = v1[q]; }
        }

        short8 fah[2], fal[2];
#pragma unroll
        for (int i = 0; i < 2; ++i) {
            fah[i] = *(const short8*)&AsH[TILE_OFF(atile + i) + lane * 8];
            fal[i] = *(const short8*)&AsL[TILE_OFF(atile + i) + lane * 8];
        }

#pragma unroll
        for (int i = 0; i < 2; ++i)
#pragma unroll
            for (int j = 0; j < 4; ++j) {
                acc[i][j] = __builtin_amdgcn_mfma_f32_16x16x32_bf16(
                    fah[i], fbh[j], acc[i][j], 0, 0, 0);
                acc[i][j] = __builtin_amdgcn_mfma_f32_16x16x32_bf16(
                    fah[i], fbl[j], acc[i][j], 0, 0, 0);
                acc[i][j] = __builtin_amdgcn_mfma_f32_16x16x32_bf16(
                    fal[i], fbh[j], acc[i][j], 0, 0, 0);
            }
    }

    // epilogue: C/D layout col=lane&15, row=quad*4+reg; scale by dis[row]
#pragma unroll
    for (int i = 0; i < 2; ++i) {
#pragma unroll
        for (int r = 0; r < 4; ++r) {
            int gr = row0 + R + i * 16 + quad * 4 + r;
            if (gr < N) {
                if (atomic) {
#pragma unroll
                    for (int j = 0; j < 4; ++j)
                        unsafeAtomicAdd(&C[(size_t)gr * 128 + Cc + j * 16 + m16],
                                        acc[i][j][r] * dr[i][r]);
                } else {
#pragma unroll
                    for (int j = 0; j < 4; ++j)
                        C[(size_t)gr * 128 + Cc + j * 16 + m16] =
                            acc[i][j][r] * dr[i][r];
                }
            }
        }
    }
}

// ---- K1: weight conversion (frag order) + degree count --------------------
__global__ void conv_deg_kernel(
    const float* __restrict__ W1, const float* __restrict__ W2,
    const float* __restrict__ Wm, const float* __restrict__ Ws,
    u16* __restrict__ B1h, u16* __restrict__ B1l,
    u16* __restrict__ B2h, u16* __restrict__ B2l,
    u16* __restrict__ Bch, u16* __restrict__ Bcl,
    const int* __restrict__ ew, int* __restrict__ deg, int E) {
    __shared__ int sflag;
    int mode = block_mode(ew, &sflag);
    int gtid = blockIdx.x * 256 + threadIdx.x;
    if (gtid < 98304) {
        int idx = gtid;
        u16 h, l;
        if (idx < 65536) {                 // W1: 512x128, ksteps=16
            int t = idx >> 13, ks = (idx >> 9) & 15, L = (idx >> 3) & 63, q = idx & 7;
            int col = t * 16 + (L & 15);
            int k = ks * 32 + (L >> 4) * 8 + q;
            split_bf16(W1[k * 128 + col], h, l);
            B1h[idx] = h; B1l[idx] = l;
        } else if (idx < 81920) {          // W2: 128x128, ksteps=4
            int o = idx - 65536;
            int t = o >> 11, ks = (o >> 9) & 3, L = (o >> 3) & 63, q = o & 7;
            int col = t * 16 + (L & 15);
            int k = ks * 32 + (L >> 4) * 8 + q;
            split_bf16(W2[k * 128 + col], h, l);
            B2h[o] = h; B2l[o] = l;
        } else {                           // [Wm|Ws]: 128x128, ksteps=4
            int o = idx - 81920;
            int t = o >> 11, ks = (o >> 9) & 3, L = (o >> 3) & 63, q = o & 7;
            int col = t * 16 + (L & 15);
            int k = ks * 32 + (L >> 4) * 8 + q;
            float f = (col < 64) ? Wm[k * 64 + col] : Ws[k * 64 + (col - 64)];
            split_bf16(f, h, l);
            Bch[o] = h; Bcl[o] = l;
        }
    }
    if (gtid < E) {
        int d = mode ? ew[2 * E + 2 * gtid] : ew[E + gtid];
        atomicAdd(&deg[d], 1);
    }
}

// ---- K2: per-chunk exclusive scan + dis = rsqrt(deg+1) --------------------
__global__ void scan_block_kernel(const int* __restrict__ deg, int* __restrict__ rowptr,
                                  int* __restrict__ aux, float* __restrict__ dis, int N) {
    __shared__ int s[256];
    int i = blockIdx.x * 256 + threadIdx.x;
    int v = (i < N) ? deg[i] : 0;
    if (i < N) dis[i] = rsqrtf((float)v + 1.0f);
    s[threadIdx.x] = v;
    __syncthreads();
    for (int off = 1; off < 256; off <<= 1) {
        int t = (threadIdx.x >= off) ? s[threadIdx.x - off] : 0;
        __syncthreads();
        s[threadIdx.x] += t;
        __syncthreads();
    }
    if (i < N) rowptr[i] = s[threadIdx.x] - v;
    if (threadIdx.x == 255) aux[blockIdx.x] = s[255];
}

// ---- K3: offsets with inline aux scan + cursor init + hA zero -------------
__global__ void offsets_kernel(int* __restrict__ rowptr, const int* __restrict__ aux,
                               int* __restrict__ cursor, float* __restrict__ hA,
                               int N, int E, int nch) {
    __shared__ int s[256];
    const int b = blockIdx.x, tid = threadIdx.x;
    int v = (tid < nch) ? aux[tid] : 0;
    s[tid] = v;
    __syncthreads();
    for (int off = 1; off < 256; off <<= 1) {
        int t = (tid >= off) ? s[tid - off] : 0;
        __syncthreads();
        s[tid] += t;
        __syncthreads();
    }
    const int excl = (b == 0) ? 0 : s[b - 1];
    int i = b * 256 + tid;
    if (i < N) {
        int rp = rowptr[i] + excl;
        rowptr[i] = rp;
        cursor[i] = rp;
    }
    if (b == 0 && tid == 0) rowptr[N] = E;
    // zero hA (split-K gemm1 accumulates into it atomically)
    f32x4* hz = (f32x4*)hA;
    const size_t nvec = (size_t)N * 32;        // N*128 floats
    const size_t step = (size_t)gridDim.x * 256;
    for (size_t z = (size_t)b * 256 + tid; z < nvec; z += step)
        hz[z] = (f32x4)0.f;
}

// ---- K4: split-K gemm1 (blocks < 2*gtiles) PARALLEL fill_csr (rest) -------
__global__ __launch_bounds__(256) void gemm1_fill_kernel(
    const float* __restrict__ A, const u16* __restrict__ Bfh,
    const u16* __restrict__ Bfl, const float* __restrict__ dis,
    float* __restrict__ C, int N, int gtiles2,
    const int* __restrict__ ew, int* __restrict__ cursor,
    int* __restrict__ csr_src, int E) {
    __shared__ __align__(16) u16 AsH[4 * 520], AsL[4 * 520];
    __shared__ int sflag;
    if ((int)blockIdx.x < gtiles2) {
        const int t = blockIdx.x >> 1;
        const int kh = blockIdx.x & 1;         // K-half: steps [kh*8, kh*8+8)
        gemm_tile(A, Bfh, Bfl, dis, C, N, 512, t, kh * 8, kh * 8 + 8, 1,
                  AsH, AsL);
    } else {
        int mode = block_mode(ew, &sflag);
        int e = ((int)blockIdx.x - gtiles2) * 256 + (int)threadIdx.x;
        if (e < E) {
            int s = mode ? ew[2 * e] : ew[e];
            int d = mode ? ew[2 * E + 2 * e] : ew[E + e];
            int pos = atomicAdd(&cursor[d], 1);
            csr_src[pos] = s;
        }
    }
}

// ---- standalone GEMM (gemm2/gemm3, K=128: short chain, plain stores) ------
__global__ __launch_bounds__(256) void gemm_mfma(const float* __restrict__ A,
                                                 const u16* __restrict__ Bfh,
                                                 const u16* __restrict__ Bfl,
                                                 const float* __restrict__ dis,
                                                 float* __restrict__ C,
                                                 int N, int K) {
    __shared__ __align__(16) u16 AsH[4 * 520], AsL[4 * 520];
    gemm_tile(A, Bfh, Bfl, dis, C, N, K, blockIdx.x, 0, K >> 5, 0, AsH, AsL);
}

// ---- propagate: one wave per node, paired-edge float4 gather --------------
// hs = dis (.) (A*W). out[v] = relu?( dis[v]*(sum_src hs[src] + hs[v]) + b ).
__global__ __launch_bounds__(256) void propagate_kernel(
    const float* __restrict__ hs, const int* __restrict__ rowptr,
    const int* __restrict__ csr_src, const float* __restrict__ dis,
    const float* __restrict__ bias, float* __restrict__ out, int N, int do_relu) {
    int wave = (blockIdx.x * 256 + threadIdx.x) >> 6;
    int lane = threadIdx.x & 63;
    if (wave >= N) return;
    const int v = wave;
    const int half = lane >> 5, c = lane & 31;
    const int f4 = c * 4;
    const float dv = dis[v];
    f32x4 acc = (f32x4)0.f;
    const int beg = rowptr[v], end = rowptr[v + 1];
    int i = beg;
    for (; i + 8 <= end; i += 8) {
        int s[4];
        f32x4 g[4];
#pragma unroll
        for (int u = 0; u < 4; ++u) s[u] = csr_src[i + 2 * u + half];
#pragma unroll
        for (int u = 0; u < 4; ++u) g[u] = *(const f32x4*)&hs[(size_t)s[u] * 128 + f4];
#pragma unroll
        for (int u = 0; u < 4; ++u) acc += g[u];
    }
    for (; i + 2 <= end; i += 2) {
        int s = csr_src[i + half];
        acc += *(const f32x4*)&hs[(size_t)s * 128 + f4];
    }
    if (i < end && half == 0) {
        int s = csr_src[i];
        acc += *(const f32x4*)&hs[(size_t)s * 128 + f4];
    }
#pragma unroll
    for (int k = 0; k < 4; ++k) acc[k] += __shfl_xor(acc[k], 32);
    if (half == 0) {
        const f32x4 hv = *(const f32x4*)&hs[(size_t)v * 128 + f4];
        const f32x4 b = *(const f32x4*)&bias[f4];
        f32x4 o;
#pragma unroll
        for (int k = 0; k < 4; ++k) {
            float t = dv * (acc[k] + hv[k]) + b[k];
            o[k] = do_relu ? fmaxf(t, 0.f) : t;
        }
        *(f32x4*)&out[(size_t)v * 128 + f4] = o;
    }
}

// ---- final propagate: split into z_mean / z_log_std -----------------------
__global__ void __launch_bounds__(256) propagate_final_kernel(
    const float* __restrict__ hs, const int* __restrict__ rowptr,
    const int* __restrict__ csr_src, const float* __restrict__ dis,
    const float* __restrict__ bm, const float* __restrict__ bs,
    float* __restrict__ out, int N) {
    int wave = (blockIdx.x * 256 + threadIdx.x) >> 6;
    int lane = threadIdx.x & 63;
    if (wave >= N) return;
    const int v = wave;
    const int half = lane >> 5, c = lane & 31;
    const int f4 = c * 4;
    const float dv = dis[v];
    f32x4 acc = (f32x4)0.f;
    const int beg = rowptr[v], end = rowptr[v + 1];
    int i = beg;
    for (; i + 8 <= end; i += 8) {
        int s[4];
        f32x4 g[4];
#pragma unroll
        for (int u = 0; u < 4; ++u) s[u] = csr_src[i + 2 * u + half];
#pragma unroll
        for (int u = 0; u < 4; ++u) g[u] = *(const f32x4*)&hs[(size_t)s[u] * 128 + f4];
#pragma unroll
        for (int u = 0; u < 4; ++u) acc += g[u];
    }
    for (; i + 2 <= end; i += 2) {
        int s = csr_src[i + half];
        acc += *(const f32x4*)&hs[(size_t)s * 128 + f4];
    }
    if (i < end && half == 0) {
        int s = csr_src[i];
        acc += *(const f32x4*)&hs[(size_t)s * 128 + f4];
    }
#pragma unroll
    for (int k = 0; k < 4; ++k) acc[k] += __shfl_xor(acc[k], 32);
    if (half == 0) {
        const f32x4 hv = *(const f32x4*)&hs[(size_t)v * 128 + f4];
        f32x4 o;
        if (f4 < 64) {                          // z_mean
            const f32x4 b = *(const f32x4*)&bm[f4];
#pragma unroll
            for (int k = 0; k < 4; ++k) o[k] = dv * (acc[k] + hv[k]) + b[k];
            *(f32x4*)&out[(size_t)v * 64 + f4] = o;
        } else {                                // z_log_std
            const int g = f4 - 64;
            const f32x4 b = *(const f32x4*)&bs[g];
#pragma unroll
            for (int k = 0; k < 4; ++k) o[k] = dv * (acc[k] + hv[k]) + b[k];
            *(f32x4*)&out[(size_t)N * 64 + (size_t)v * 64 + g] = o;
        }
    }
}

extern "C" void kernel_launch(void* const* d_in, const int* in_sizes, int n_in,
                              void* d_out, int out_size, void* d_ws, size_t ws_size,
                              hipStream_t stream) {
    const float* x  = (const float*)d_in[0];
    const int*   ew = (const int*)d_in[1];
    const float* W1 = (const float*)d_in[2];
    const float* b1 = (const float*)d_in[3];
    const float* W2 = (const float*)d_in[4];
    const float* b2 = (const float*)d_in[5];
    const float* Wm = (const float*)d_in[6];
    const float* bm = (const float*)d_in[7];
    const float* Ws = (const float*)d_in[8];
    const float* bs = (const float*)d_in[9];
    float* out = (float*)d_out;

    const int IN = 512, H = 128;
    const int N = in_sizes[0] / IN;     // 50000
    const int E = in_sizes[1] / 2;      // 800000

    // ---- workspace (~55.6 MB < proven-safe 58.47 MB) -----------------------
    char* base = (char*)d_ws;
    size_t off = 0;
    auto alloc = [&](size_t bytes) -> char* {
        char* p = base + off;
        off = (off + bytes + 255) & ~(size_t)255;
        return p;
    };
    int*   deg     = (int*)  alloc((size_t)N * 4);      // zeroed by memset
    int*   cursor  = (int*)  alloc((size_t)N * 4);      // init in offsets
    float* dis     = (float*)alloc((size_t)N * 4);
    int*   rowptr  = (int*)  alloc((size_t)(N + 1) * 4);
    int*   aux     = (int*)  alloc(256 * 4);
    int*   csr_src = (int*)  alloc((size_t)E * 4);
    u16*   B1h     = (u16*)  alloc((size_t)IN * H * 2);
    u16*   B1l     = (u16*)  alloc((size_t)IN * H * 2);
    u16*   B2h     = (u16*)  alloc((size_t)H * H * 2);
    u16*   B2l     = (u16*)  alloc((size_t)H * H * 2);
    u16*   Bch     = (u16*)  alloc((size_t)H * H * 2);
    u16*   Bcl     = (u16*)  alloc((size_t)H * H * 2);
    float* hA      = (float*)alloc((size_t)N * H * 4);
    float* hB      = (float*)alloc((size_t)N * H * 4);
    (void)ws_size; (void)n_in; (void)out_size;

    (void)hipMemsetAsync(deg, 0, (size_t)N * 4, stream);

    const int eblocks = (E + 255) / 256;
    const int nblocks = (N + 255) / 256;
    const int nch = nblocks;
    const int gtiles = (N + 63) / 64;
    const int pblocks = (N * 64 + 255) / 256;

    // K1: conv + deg
    conv_deg_kernel<<<eblocks, 256, 0, stream>>>(
        W1, W2, Wm, Ws, B1h, B1l, B2h, B2l, Bch, Bcl, ew, deg, E);
    // K2: chunk scan + dis
    scan_block_kernel<<<nblocks, 256, 0, stream>>>(deg, rowptr, aux, dis, N);
    // K3: offsets (inline aux scan) + cursor init + hA zero
    offsets_kernel<<<nblocks, 256, 0, stream>>>(rowptr, aux, cursor, hA, N, E, nch);
    // K4: split-K(2) gemm1 || fill_csr
    gemm1_fill_kernel<<<2 * gtiles + eblocks, 256, 0, stream>>>(
        x, B1h, B1l, dis, hA, N, 2 * gtiles, ew, cursor, csr_src, E);
    // K5..K9
    propagate_kernel<<<pblocks, 256, 0, stream>>>(hA, rowptr, csr_src, dis,
                                                  b1, hB, N, 1);
    gemm_mfma<<<gtiles, 256, 0, stream>>>(hB, B2h, B2l, dis, hA, N, H);
    propagate_kernel<<<pblocks, 256, 0, stream>>>(hA, rowptr, csr_src, dis,
                                                  b2, hB, N, 1);
    gemm_mfma<<<gtiles, 256, 0, stream>>>(hB, Bch, Bcl, dis, hA, N, H);
    propagate_final_kernel<<<pblocks, 256, 0, stream>>>(hA, rowptr, csr_src, dis,
                                                        bm, bs, out, N);
}